// Round 3
// baseline (85.057 us; speedup 1.0000x reference)
//
#include <hip/hip_runtime.h>
#include <math.h>

#define EPSV 1e-6f

// ---------------------------------------------------------------------------
// K1: per-batch length from first negative mask entry + pool counter seed.
// grid = B blocks x 256 threads.
// ---------------------------------------------------------------------------
__global__ void len_kernel(const float* __restrict__ mask,
                           int* __restrict__ lens, int* __restrict__ ctr,
                           int T, int seed) {
    const int b = blockIdx.x;
    const float* m = mask + (size_t)b * T;
    int local = T;
    for (int t = threadIdx.x; t < T; t += blockDim.x) {
        if (m[t] < 0.0f) local = min(local, t);
    }
    __shared__ int s[256];
    s[threadIdx.x] = local;
    __syncthreads();
    #pragma unroll
    for (int off = 128; off > 0; off >>= 1) {
        if ((int)threadIdx.x < off)
            s[threadIdx.x] = min(s[threadIdx.x], s[threadIdx.x + off]);
        __syncthreads();
    }
    if (threadIdx.x == 0) {
        int first = s[0];
        lens[b] = (first < T) ? (first + 1) : T;
        if (b == 0) ctr[0] = seed;   // pool counter starts past the seeds
    }
}

// ---------------------------------------------------------------------------
// K2: persistent work-stealing partial sums.
// grid = NB blocks x D4 threads. Units are (b, c) proportional chunks:
// rows [c*len/CPB, (c+1)*len/CPB) of batch b -- 32..64 valid rows each.
// First unit = blockIdx.x (static seed); subsequent units popped with an
// atomicAdd issued BEFORE processing the current unit (latency hidden).
// Each unit writes its own psum/psq slot -> output is bit-deterministic
// regardless of which block processes which unit.
// ---------------------------------------------------------------------------
__global__ void partial_kernel(const float* __restrict__ feat,
                               const int* __restrict__ lens,
                               int* __restrict__ ctr,
                               float4* __restrict__ psum,
                               float4* __restrict__ psq,
                               int CPB, int NU, int T, int D4) {
    __shared__ int s_next;
    const int d4 = threadIdx.x;
    int unit = blockIdx.x;

    while (unit < NU) {
        __syncthreads();                       // s_next from prev iter consumed
        if (threadIdx.x == 0) s_next = atomicAdd(ctr, 1);

        const int b = unit / CPB;
        const int c = unit - b * CPB;
        const int len = lens[b];
        const int t0 = (int)(((long long)c * len) / CPB);
        const int t1 = (int)(((long long)(c + 1) * len) / CPB);

        const float4* f = (const float4*)feat + (size_t)b * T * D4;

        float4 sm = make_float4(0.f, 0.f, 0.f, 0.f);
        float4 sq = make_float4(0.f, 0.f, 0.f, 0.f);

        #pragma unroll 8
        for (int t = t0; t < t1; ++t) {
            float4 v = f[(size_t)t * D4 + d4];
            sm.x += v.x; sm.y += v.y; sm.z += v.z; sm.w += v.w;
            sq.x = fmaf(v.x, v.x, sq.x);
            sq.y = fmaf(v.y, v.y, sq.y);
            sq.z = fmaf(v.z, v.z, sq.z);
            sq.w = fmaf(v.w, v.w, sq.w);
        }

        const size_t idx = (size_t)unit * D4 + d4;
        psum[idx] = sm;
        psq[idx]  = sq;

        __syncthreads();                       // s_next now valid for everyone
        unit = s_next;
    }
}

// ---------------------------------------------------------------------------
// K3: reduce CPB partials per batch, finalize mean / sqrt-var, write [B, 2D].
// grid = B blocks x D4 threads. CPB independent loads per thread -> pipelined.
// ---------------------------------------------------------------------------
__global__ void final_kernel(const float4* __restrict__ psum,
                             const float4* __restrict__ psq,
                             const int* __restrict__ lens,
                             float* __restrict__ out,
                             int CPB, int D4) {
    const int b  = blockIdx.x;
    const int d4 = threadIdx.x;

    float4 s = make_float4(0.f, 0.f, 0.f, 0.f);
    float4 q = make_float4(0.f, 0.f, 0.f, 0.f);
    for (int c = 0; c < CPB; ++c) {
        size_t idx = ((size_t)b * CPB + c) * D4 + d4;
        float4 v = psum[idx];
        float4 w = psq[idx];
        s.x += v.x; s.y += v.y; s.z += v.z; s.w += v.w;
        q.x += w.x; q.y += w.y; q.z += w.z; q.w += w.w;
    }

    const float inv = 1.0f / (float)lens[b];
    float4 mean, var;
    mean.x = s.x * inv; mean.y = s.y * inv; mean.z = s.z * inv; mean.w = s.w * inv;
    var.x = sqrtf(fmaf(-mean.x, mean.x, q.x * inv) + EPSV);
    var.y = sqrtf(fmaf(-mean.y, mean.y, q.y * inv) + EPSV);
    var.z = sqrtf(fmaf(-mean.z, mean.z, q.z * inv) + EPSV);
    var.w = sqrtf(fmaf(-mean.w, mean.w, q.w * inv) + EPSV);

    const int D = D4 * 4;
    float4* orow = (float4*)(out + (size_t)b * 2 * D);
    orow[d4]      = mean;   // [0, D)
    orow[D4 + d4] = var;    // [D, 2D)
}

// ---------------------------------------------------------------------------
extern "C" void kernel_launch(void* const* d_in, const int* in_sizes, int n_in,
                              void* d_out, int out_size, void* d_ws, size_t ws_size,
                              hipStream_t stream) {
    const float* feature  = (const float*)d_in[0];
    const float* att_mask = (const float*)d_in[1];
    float* out = (float*)d_out;

    // Shapes: in_sizes[0] = B*T*D, in_sizes[1] = B*T, out_size = B*2D
    const int D  = (int)((long long)in_sizes[0] / in_sizes[1]);   // 768
    const int B  = out_size / (2 * D);                             // 64
    const int T  = in_sizes[1] / B;                                // 2048
    const int D4 = D / 4;                                          // 192

    // Workspace layout:
    //   [0, 256)      pool counter
    //   [256, 4096)   lens (B ints)
    //   [4096, ...)   psum, psq: NU * D4 float4 each
    int* ctr  = (int*)d_ws;
    int* lens = (int*)((char*)d_ws + 256);

    const size_t per_chunk_bytes = (size_t)B * D4 * sizeof(float4) * 2;
    int CPB = 32;
    if (ws_size >= 4096 + per_chunk_bytes) {
        int fit = (int)((ws_size - 4096) / per_chunk_bytes);
        if (fit < CPB) CPB = fit;
    } else {
        CPB = 1;
    }
    if (CPB < 1) CPB = 1;
    const int NU = B * CPB;

    float4* psum = (float4*)((char*)d_ws + 4096);
    float4* psq  = psum + (size_t)NU * D4;

    const int NB = 1024;   // 4 blocks/CU x 256 CUs, all co-resident

    len_kernel<<<B, 256, 0, stream>>>(att_mask, lens, ctr, T, NB);
    partial_kernel<<<NB, D4, 0, stream>>>(feature, lens, ctr, psum, psq,
                                          CPB, NU, T, D4);
    final_kernel<<<B, D4, 0, stream>>>(psum, psq, lens, out, CPB, D4);
}

// Round 4
// 84.001 us; speedup vs baseline: 1.0126x; 1.0126x over previous
//
#include <hip/hip_runtime.h>
#include <math.h>
#include <limits.h>

#define EPSV 1e-6f

// ---------------------------------------------------------------------------
// K1: per-batch length from first negative mask entry. grid = B x 256.
// ---------------------------------------------------------------------------
__global__ void len_kernel(const float* __restrict__ mask,
                           int* __restrict__ lens, int T) {
    const int b = blockIdx.x;
    const float* m = mask + (size_t)b * T;
    int local = T;
    if ((T & 3) == 0) {
        const float4* m4 = (const float4*)m;
        const int T4 = T >> 2;
        for (int i = threadIdx.x; i < T4; i += blockDim.x) {
            float4 v = m4[i];
            if (v.x < 0.f) local = min(local, 4 * i);
            if (v.y < 0.f) local = min(local, 4 * i + 1);
            if (v.z < 0.f) local = min(local, 4 * i + 2);
            if (v.w < 0.f) local = min(local, 4 * i + 3);
        }
    } else {
        for (int t = threadIdx.x; t < T; t += blockDim.x)
            if (m[t] < 0.f) local = min(local, t);
    }
    __shared__ int s[256];
    s[threadIdx.x] = local;
    __syncthreads();
    #pragma unroll
    for (int off = 128; off > 0; off >>= 1) {
        if ((int)threadIdx.x < off)
            s[threadIdx.x] = min(s[threadIdx.x], s[threadIdx.x + off]);
        __syncthreads();
    }
    if (threadIdx.x == 0) {
        int first = s[0];
        lens[b] = (first < T) ? (first + 1) : T;
    }
}

// ---------------------------------------------------------------------------
// K2: exactly-balanced partial sums over the flat valid-row space.
// grid = NB x D4. Block i owns flat valid rows [i*V/NB, (i+1)*V/NB) -- every
// block processes the same row count (+-1), so every CU gets identical work.
// A block's range maps to <= `segs` (batch, row-range) segments; each segment
// writes its own tagged slot -> bit-deterministic regardless of scheduling.
// ---------------------------------------------------------------------------
__global__ void partial_kernel(const float* __restrict__ feat,
                               const int* __restrict__ lens,
                               int* __restrict__ tags,
                               float4* __restrict__ psum,
                               float4* __restrict__ psq,
                               int B, int T, int D4, int NB, int segs) {
    __shared__ int s_pre[1025];   // exclusive prefix of lens; B <= 1024
    const int tid = threadIdx.x;
    const int bid = blockIdx.x;

    // parallel load of lens, then tiny serial scan in LDS (B is small)
    if (tid <= B) s_pre[tid] = (tid < B) ? lens[tid] : 0;
    __syncthreads();
    if (tid == 0) {
        int acc = 0;
        for (int i = 0; i < B; ++i) { int l = s_pre[i]; s_pre[i] = acc; acc += l; }
        s_pre[B] = acc;
    }
    __syncthreads();

    const int V = s_pre[B];
    const long long r0 = (long long)bid * V / NB;
    const long long r1 = (long long)(bid + 1) * V / NB;

    // binary search: b with s_pre[b] <= r0 < s_pre[b+1]
    int lo = 0, hi = B;
    while (hi - lo > 1) {
        int mid = (lo + hi) >> 1;
        if ((long long)s_pre[mid] <= r0) lo = mid; else hi = mid;
    }
    int b = lo;
    int seg = 0;
    long long r = r0;
    const int d4 = tid;

    while (r < r1 && seg < segs) {
        const int lenb = s_pre[b + 1] - s_pre[b];
        const int t0 = (int)(r - s_pre[b]);
        const long long te = r1 - s_pre[b];
        const int t1 = (int)(te < (long long)lenb ? te : (long long)lenb);

        const float4* f = (const float4*)feat + (size_t)b * T * D4;
        float4 sm = make_float4(0.f, 0.f, 0.f, 0.f);
        float4 sq = make_float4(0.f, 0.f, 0.f, 0.f);

        #pragma unroll 8
        for (int t = t0; t < t1; ++t) {
            float4 v = f[(size_t)t * D4 + d4];
            sm.x += v.x; sm.y += v.y; sm.z += v.z; sm.w += v.w;
            sq.x = fmaf(v.x, v.x, sq.x);
            sq.y = fmaf(v.y, v.y, sq.y);
            sq.z = fmaf(v.z, v.z, sq.z);
            sq.w = fmaf(v.w, v.w, sq.w);
        }

        const size_t slot = (size_t)bid * segs + seg;
        psum[slot * D4 + d4] = sm;
        psq[slot * D4 + d4]  = sq;
        if (tid == 0) tags[slot] = b;

        r = (long long)s_pre[b] + t1;
        ++b; ++seg;
    }
    if (tid == 0)
        for (; seg < segs; ++seg) tags[(size_t)bid * segs + seg] = -1;
}

// ---------------------------------------------------------------------------
// K3: per batch, reduce its (contiguous) tagged slots, finalize, write [B,2D].
// grid = B x D4. Slot range found by deterministic min/max reduction.
// ---------------------------------------------------------------------------
__global__ void final_kernel(const float4* __restrict__ psum,
                             const float4* __restrict__ psq,
                             const int* __restrict__ tags,
                             const int* __restrict__ lens,
                             float* __restrict__ out,
                             int NS, int D4) {
    const int b   = blockIdx.x;
    const int tid = threadIdx.x;

    int mn = INT_MAX, mx = -1;
    for (int u = tid; u < NS; u += blockDim.x) {
        if (tags[u] == b) { mn = min(mn, u); mx = max(mx, u); }
    }
    __shared__ int smn[256], smx[256];
    smn[tid] = mn; smx[tid] = mx;
    if (tid < 256 - (int)blockDim.x) {
        smn[blockDim.x + tid] = INT_MAX;
        smx[blockDim.x + tid] = -1;
    }
    __syncthreads();
    #pragma unroll
    for (int off = 128; off > 0; off >>= 1) {
        if (tid < off) {
            smn[tid] = min(smn[tid], smn[tid + off]);
            smx[tid] = max(smx[tid], smx[tid + off]);
        }
        __syncthreads();
    }
    const int u0 = smn[0], u1 = smx[0];

    float4 s = make_float4(0.f, 0.f, 0.f, 0.f);
    float4 q = make_float4(0.f, 0.f, 0.f, 0.f);
    for (int u = u0; u <= u1; ++u) {        // u0 > u1 only if batch empty
        if (tags[u] == b) {
            float4 v = psum[(size_t)u * D4 + tid];
            float4 w = psq[(size_t)u * D4 + tid];
            s.x += v.x; s.y += v.y; s.z += v.z; s.w += v.w;
            q.x += w.x; q.y += w.y; q.z += w.z; q.w += w.w;
        }
    }

    const float inv = 1.0f / (float)lens[b];
    float4 mean, var;
    mean.x = s.x * inv; mean.y = s.y * inv; mean.z = s.z * inv; mean.w = s.w * inv;
    var.x = sqrtf(fmaf(-mean.x, mean.x, q.x * inv) + EPSV);
    var.y = sqrtf(fmaf(-mean.y, mean.y, q.y * inv) + EPSV);
    var.z = sqrtf(fmaf(-mean.z, mean.z, q.z * inv) + EPSV);
    var.w = sqrtf(fmaf(-mean.w, mean.w, q.w * inv) + EPSV);

    const int D = D4 * 4;
    float4* orow = (float4*)(out + (size_t)b * 2 * D);
    orow[tid]      = mean;   // [0, D)
    orow[D4 + tid] = var;    // [D, 2D)
}

// ---------------------------------------------------------------------------
extern "C" void kernel_launch(void* const* d_in, const int* in_sizes, int n_in,
                              void* d_out, int out_size, void* d_ws, size_t ws_size,
                              hipStream_t stream) {
    const float* feature  = (const float*)d_in[0];
    const float* att_mask = (const float*)d_in[1];
    float* out = (float*)d_out;

    // Shapes: in_sizes[0] = B*T*D, in_sizes[1] = B*T, out_size = B*2D
    const int D  = (int)((long long)in_sizes[0] / in_sizes[1]);   // 768
    const int B  = out_size / (2 * D);                             // 64
    const int T  = in_sizes[1] / B;                                // 2048
    const int D4 = D / 4;                                          // 192

    // Pick NB (blocks) and segs (slots/block) to fit workspace.
    // ws layout: [0,8192) lens | tags (NS ints, 256-aligned end) | psum | psq
    int NB = 1024, segs = 4;
    size_t tag_off = 8192, data_off = 0, need = 0;
    for (;;) {
        const size_t NS = (size_t)NB * segs;
        data_off = (tag_off + NS * sizeof(int) + 255) & ~(size_t)255;
        need = data_off + NS * D4 * sizeof(float4) * 2;
        if (need <= ws_size || NB <= 64) break;
        if (segs > 2) segs = 2; else NB >>= 1;
    }
    const int NS = NB * segs;

    int*    lens = (int*)d_ws;
    int*    tags = (int*)((char*)d_ws + tag_off);
    float4* psum = (float4*)((char*)d_ws + data_off);
    float4* psq  = psum + (size_t)NS * D4;

    len_kernel<<<B, 256, 0, stream>>>(att_mask, lens, T);
    partial_kernel<<<NB, D4, 0, stream>>>(feature, lens, tags, psum, psq,
                                          B, T, D4, NB, segs);
    final_kernel<<<B, D4, 0, stream>>>(psum, psq, tags, lens, out, NS, D4);
}

// Round 5
// 77.779 us; speedup vs baseline: 1.0936x; 1.0800x over previous
//
#include <hip/hip_runtime.h>
#include <math.h>

#define EPSV 1e-6f

// ---------------------------------------------------------------------------
// K1: per-batch length from first negative mask entry. grid = B x 256.
// ---------------------------------------------------------------------------
__global__ void len_kernel(const float* __restrict__ mask,
                           int* __restrict__ lens, int T) {
    const int b = blockIdx.x;
    const float* m = mask + (size_t)b * T;
    int local = T;
    if ((T & 3) == 0) {
        const float4* m4 = (const float4*)m;
        const int T4 = T >> 2;
        for (int i = threadIdx.x; i < T4; i += blockDim.x) {
            float4 v = m4[i];
            if (v.x < 0.f) local = min(local, 4 * i);
            if (v.y < 0.f) local = min(local, 4 * i + 1);
            if (v.z < 0.f) local = min(local, 4 * i + 2);
            if (v.w < 0.f) local = min(local, 4 * i + 3);
        }
    } else {
        for (int t = threadIdx.x; t < T; t += blockDim.x)
            if (m[t] < 0.f) local = min(local, t);
    }
    __shared__ int s[256];
    s[threadIdx.x] = local;
    __syncthreads();
    #pragma unroll
    for (int off = 128; off > 0; off >>= 1) {
        if ((int)threadIdx.x < off)
            s[threadIdx.x] = min(s[threadIdx.x], s[threadIdx.x + off]);
        __syncthreads();
    }
    if (threadIdx.x == 0) {
        int first = s[0];
        lens[b] = (first < T) ? (first + 1) : T;
    }
}

// ---------------------------------------------------------------------------
// K2: straight-line partial sums. grid = (nchunk, B); block = D4 threads.
// Chunk c of batch b covers rows [c*len/nchunk, (c+1)*len/nchunk).
// nchunk=64 -> 4096 blocks (~16/CU vs ~10 resident): oversubscription lets
// the HW scheduler backfill early-finishing CUs (dynamic smoothing) without
// any in-kernel loop/sync structure (R3/R4 lesson: keep the body straight-line).
// ---------------------------------------------------------------------------
__global__ __launch_bounds__(192) void partial_kernel(
        const float* __restrict__ feat,
        const int* __restrict__ lens,
        float4* __restrict__ psum,
        float4* __restrict__ psq,
        int nchunk, int T, int D4) {
    const int c = blockIdx.x;
    const int b = blockIdx.y;
    const int len = lens[b];
    const int t0 = (int)(((long long)c * len) / nchunk);
    const int t1 = (int)(((long long)(c + 1) * len) / nchunk);

    const float4* f = (const float4*)feat + (size_t)b * T * D4;
    const int d4 = threadIdx.x;

    float4 sm = make_float4(0.f, 0.f, 0.f, 0.f);
    float4 sq = make_float4(0.f, 0.f, 0.f, 0.f);

    #pragma unroll 8
    for (int t = t0; t < t1; ++t) {
        float4 v = f[(size_t)t * D4 + d4];
        sm.x += v.x; sm.y += v.y; sm.z += v.z; sm.w += v.w;
        sq.x = fmaf(v.x, v.x, sq.x);
        sq.y = fmaf(v.y, v.y, sq.y);
        sq.z = fmaf(v.z, v.z, sq.z);
        sq.w = fmaf(v.w, v.w, sq.w);
    }

    const size_t slot = ((size_t)b * nchunk + c) * D4 + d4;
    psum[slot] = sm;
    psq[slot]  = sq;
}

// ---------------------------------------------------------------------------
// K3: reduce nchunk partials per batch (fixed order -> deterministic),
// finalize mean / sqrt-var, write [B, 2D]. grid = B x D4.
// ---------------------------------------------------------------------------
__global__ __launch_bounds__(192) void final_kernel(
        const float4* __restrict__ psum,
        const float4* __restrict__ psq,
        const int* __restrict__ lens,
        float* __restrict__ out,
        int nchunk, int D4) {
    const int b  = blockIdx.x;
    const int d4 = threadIdx.x;

    const float4* ps = psum + (size_t)b * nchunk * D4 + d4;
    const float4* pq = psq  + (size_t)b * nchunk * D4 + d4;

    float4 s = make_float4(0.f, 0.f, 0.f, 0.f);
    float4 q = make_float4(0.f, 0.f, 0.f, 0.f);
    #pragma unroll 4
    for (int c = 0; c < nchunk; ++c) {
        float4 v = ps[(size_t)c * D4];
        float4 w = pq[(size_t)c * D4];
        s.x += v.x; s.y += v.y; s.z += v.z; s.w += v.w;
        q.x += w.x; q.y += w.y; q.z += w.z; q.w += w.w;
    }

    const float inv = 1.0f / (float)lens[b];
    float4 mean, var;
    mean.x = s.x * inv; mean.y = s.y * inv; mean.z = s.z * inv; mean.w = s.w * inv;
    var.x = sqrtf(fmaf(-mean.x, mean.x, q.x * inv) + EPSV);
    var.y = sqrtf(fmaf(-mean.y, mean.y, q.y * inv) + EPSV);
    var.z = sqrtf(fmaf(-mean.z, mean.z, q.z * inv) + EPSV);
    var.w = sqrtf(fmaf(-mean.w, mean.w, q.w * inv) + EPSV);

    const int D = D4 * 4;
    float4* orow = (float4*)(out + (size_t)b * 2 * D);
    orow[d4]      = mean;   // [0, D)
    orow[D4 + d4] = var;    // [D, 2D)
}

// ---------------------------------------------------------------------------
extern "C" void kernel_launch(void* const* d_in, const int* in_sizes, int n_in,
                              void* d_out, int out_size, void* d_ws, size_t ws_size,
                              hipStream_t stream) {
    const float* feature  = (const float*)d_in[0];
    const float* att_mask = (const float*)d_in[1];
    float* out = (float*)d_out;

    // Shapes: in_sizes[0] = B*T*D, in_sizes[1] = B*T, out_size = B*2D
    const int D  = (int)((long long)in_sizes[0] / in_sizes[1]);   // 768
    const int B  = out_size / (2 * D);                             // 64
    const int T  = in_sizes[1] / B;                                // 2048
    const int D4 = D / 4;                                          // 192

    // Workspace: [0,4096) lens | psum | psq  (NS = B*nchunk slots of D4 float4)
    int nchunk = 64;
    size_t need;
    for (;;) {
        const size_t NS = (size_t)B * nchunk;
        need = 4096 + NS * D4 * sizeof(float4) * 2;
        if (need <= ws_size || nchunk <= 1) break;
        nchunk >>= 1;
    }

    int*    lens = (int*)d_ws;
    float4* psum = (float4*)((char*)d_ws + 4096);
    float4* psq  = psum + (size_t)B * nchunk * D4;

    len_kernel<<<B, 256, 0, stream>>>(att_mask, lens, T);
    dim3 grid(nchunk, B);
    partial_kernel<<<grid, D4, 0, stream>>>(feature, lens, psum, psq,
                                            nchunk, T, D4);
    final_kernel<<<B, D4, 0, stream>>>(psum, psq, lens, out, nchunk, D4);
}